// Round 2
// baseline (1090.925 us; speedup 1.0000x reference)
//
#include <hip/hip_runtime.h>
#include <math.h>

// WfcNN: B=262144 samples.
//   h1 = tanh(x @ W0 + b0)            (B,128)
//   h2 = tanh(h1 @ W1 + b1)           (B,64)
//   g  = tanh(h2 . Wa[eid] + ba[eid]) (B,32)
//   psi= g . Wb[eid] + bb[eid]        (B,2) ; out = psi / sqrt(|psi|^2+1e-6)
// eid = (n-1)n(2n-1)/6 + l*l + l + m  (30 experts)
//
// Round 2: expert bucketing. R1 showed VALUBusy=41% @246us (fp32 floor ~37us);
// primary suspect = TA serialization on divergent Wa gathers (~22 eids/wave x
// 512 loads/thread). Counting-sort samples by eid (hist -> scan -> scatter),
// then the compute kernel runs over sorted order: Wa loads become wave-uniform
// 1-line broadcasts (L1-resident, 8KB/expert). Also occupancy: bounds (256,4),
// LDS stride 128 (broadcast reads cannot bank-conflict) -> 35KB, 4 blocks/CU.

#define THREADS 256
#define NE 30
#define HB 256   // histogram blocks (B/HB samples per block)

__device__ __forceinline__ int expert_id(int nn, int ll, int mm) {
    return ((nn - 1) * nn * (2 * nn - 1)) / 6 + ll * ll + ll + mm;
}

__device__ __forceinline__ float fast_tanh(float v) {
    v = fminf(fmaxf(v, -15.0f), 15.0f);
    float e = __expf(2.0f * v);
    return (e - 1.0f) * __builtin_amdgcn_rcpf(e + 1.0f);
}

// ---- P1: per-block expert histogram ----
__global__ void hist_kernel(const int* __restrict__ nq, const int* __restrict__ lq,
                            const int* __restrict__ mq, int* __restrict__ hist, int B) {
    __shared__ int h[NE];
    const int tid = threadIdx.x;
    if (tid < NE) h[tid] = 0;
    __syncthreads();
    const int per = B / gridDim.x;
    const int base = blockIdx.x * per;
    for (int i = tid; i < per; i += blockDim.x) {
        const int idx = base + i;
        atomicAdd(&h[expert_id(nq[idx], lq[idx], mq[idx])], 1);
    }
    __syncthreads();
    if (tid < NE) hist[blockIdx.x * NE + tid] = h[tid];
}

// ---- P2: scan -> per-(block,expert) base offsets (single block) ----
__global__ void scan_kernel(const int* __restrict__ hist, int* __restrict__ base, int nb) {
    __shared__ int tot[NE];
    __shared__ int off[NE];
    const int t = threadIdx.x;
    if (t < NE) {
        int s = 0;
        for (int b = 0; b < nb; ++b) s += hist[b * NE + t];
        tot[t] = s;
    }
    __syncthreads();
    if (t == 0) {
        int acc = 0;
        for (int e = 0; e < NE; ++e) { off[e] = acc; acc += tot[e]; }
    }
    __syncthreads();
    if (t < NE) {
        int acc = off[t];
        for (int b = 0; b < nb; ++b) { base[b * NE + t] = acc; acc += hist[b * NE + t]; }
    }
}

// ---- P3: scatter sample indices into sorted order ----
__global__ void scatter_kernel(const int* __restrict__ nq, const int* __restrict__ lq,
                               const int* __restrict__ mq, const int* __restrict__ base,
                               int* __restrict__ perm, int* __restrict__ eids, int B) {
    __shared__ int cnt[NE];
    const int tid = threadIdx.x;
    if (tid < NE) cnt[tid] = base[blockIdx.x * NE + tid];
    __syncthreads();
    const int per = B / gridDim.x;
    const int blk = blockIdx.x * per;
    for (int i = tid; i < per; i += blockDim.x) {
        const int idx = blk + i;
        const int eid = expert_id(nq[idx], lq[idx], mq[idx]);
        const int dst = atomicAdd(&cnt[eid], 1);
        perm[dst] = idx;
        eids[dst] = eid;
    }
}

// ---- C: fused MLP over sorted sample order ----
__global__ __launch_bounds__(THREADS, 4) void wfc_kernel(
    const float* __restrict__ x,
    const int* __restrict__ perm, const int* __restrict__ eids,
    const float* __restrict__ W0, const float* __restrict__ b0,
    const float* __restrict__ W1, const float* __restrict__ b1,
    const float* __restrict__ Wa, const float* __restrict__ ba,
    const float* __restrict__ Wb, const float* __restrict__ bb,
    float* __restrict__ out)
{
    __shared__ float sW0[3 * 128];
    __shared__ float sb0[128];
    __shared__ float sW1t[64 * 128];   // [j][k] transposed; broadcast reads -> no conflicts
    __shared__ float sb1[64];

    const int tid = threadIdx.x;

    for (int i = tid; i < 3 * 128; i += THREADS) sW0[i] = W0[i];
    if (tid < 128) sb0[tid] = b0[tid];
    if (tid < 64)  sb1[tid] = b1[tid];
    for (int i = tid; i < 128 * 64; i += THREADS) {
        int k = i >> 6, j = i & 63;           // W1 is (128,64) row-major
        sW1t[j * 128 + k] = W1[i];
    }
    __syncthreads();

    const int pos = blockIdx.x * THREADS + tid;
    const int idx = perm[pos];
    const int eid = eids[pos];

    const float x0 = x[idx * 3 + 0];
    const float x1 = x[idx * 3 + 1];
    const float x2 = x[idx * 3 + 2];

    // ---- layer 1: h1[128] in registers ----
    float h1[128];
    {
        const float4* w0r0 = (const float4*)(sW0);
        const float4* w0r1 = (const float4*)(sW0 + 128);
        const float4* w0r2 = (const float4*)(sW0 + 256);
        const float4* b0v  = (const float4*)(sb0);
#pragma unroll
        for (int kv = 0; kv < 32; ++kv) {
            float4 a = w0r0[kv], b = w0r1[kv], c = w0r2[kv], bv = b0v[kv];
            h1[4 * kv + 0] = fast_tanh(fmaf(x0, a.x, fmaf(x1, b.x, fmaf(x2, c.x, bv.x))));
            h1[4 * kv + 1] = fast_tanh(fmaf(x0, a.y, fmaf(x1, b.y, fmaf(x2, c.y, bv.y))));
            h1[4 * kv + 2] = fast_tanh(fmaf(x0, a.z, fmaf(x1, b.z, fmaf(x2, c.z, bv.z))));
            h1[4 * kv + 3] = fast_tanh(fmaf(x0, a.w, fmaf(x1, b.w, fmaf(x2, c.w, bv.w))));
        }
    }

    // ---- expert bias into g[32] ----
    float g[32];
    {
        const float4* bav = (const float4*)(ba + (eid << 5));
#pragma unroll
        for (int hv = 0; hv < 8; ++hv) {
            float4 b = bav[hv];
            g[4 * hv + 0] = b.x; g[4 * hv + 1] = b.y;
            g[4 * hv + 2] = b.z; g[4 * hv + 3] = b.w;
        }
    }

    // ---- fused layer2 + expert-A (Wa loads are wave-uniform after sort) ----
    const float4* wa = (const float4*)(Wa + (size_t)eid * 2048);
#pragma unroll 2
    for (int d = 0; d < 64; ++d) {
        const float4* wrow = (const float4*)(&sW1t[d * 128]);
        float a0 = 0.f, a1 = 0.f, a2 = 0.f, a3 = 0.f;
#pragma unroll
        for (int kv = 0; kv < 32; ++kv) {
            float4 w = wrow[kv];
            a0 = fmaf(h1[4 * kv + 0], w.x, a0);
            a1 = fmaf(h1[4 * kv + 1], w.y, a1);
            a2 = fmaf(h1[4 * kv + 2], w.z, a2);
            a3 = fmaf(h1[4 * kv + 3], w.w, a3);
        }
        const float hd = fast_tanh(sb1[d] + ((a0 + a1) + (a2 + a3)));
        const float4* wav = wa + d * 8;
#pragma unroll
        for (int hv = 0; hv < 8; ++hv) {
            float4 w = wav[hv];
            g[4 * hv + 0] = fmaf(hd, w.x, g[4 * hv + 0]);
            g[4 * hv + 1] = fmaf(hd, w.y, g[4 * hv + 1]);
            g[4 * hv + 2] = fmaf(hd, w.z, g[4 * hv + 2]);
            g[4 * hv + 3] = fmaf(hd, w.w, g[4 * hv + 3]);
        }
    }

#pragma unroll
    for (int h = 0; h < 32; ++h) g[h] = fast_tanh(g[h]);

    // ---- expert-B ----
    const float2 bbv = ((const float2*)bb)[eid];
    float p0 = bbv.x, p1 = bbv.y;
    {
        const float4* wbv = (const float4*)(Wb + (eid << 6));
#pragma unroll
        for (int hv = 0; hv < 16; ++hv) {
            float4 w = wbv[hv];
            p0 = fmaf(g[2 * hv + 0], w.x, p0);
            p1 = fmaf(g[2 * hv + 0], w.y, p1);
            p0 = fmaf(g[2 * hv + 1], w.z, p0);
            p1 = fmaf(g[2 * hv + 1], w.w, p1);
        }
    }

    const float s = fmaf(p0, p0, fmaf(p1, p1, 1e-6f));
    const float inv = 1.0f / sqrtf(s);
    float2 o; o.x = p0 * inv; o.y = p1 * inv;
    ((float2*)out)[idx] = o;   // scatter to original position
}

extern "C" void kernel_launch(void* const* d_in, const int* in_sizes, int n_in,
                              void* d_out, int out_size, void* d_ws, size_t ws_size,
                              hipStream_t stream) {
    const float* x  = (const float*)d_in[0];
    const int*   n  = (const int*)d_in[1];
    const int*   l  = (const int*)d_in[2];
    const int*   m  = (const int*)d_in[3];
    const float* W0 = (const float*)d_in[4];
    const float* b0 = (const float*)d_in[5];
    const float* W1 = (const float*)d_in[6];
    const float* b1 = (const float*)d_in[7];
    const float* Wa = (const float*)d_in[8];
    const float* ba = (const float*)d_in[9];
    const float* Wb = (const float*)d_in[10];
    const float* bb = (const float*)d_in[11];
    float* out = (float*)d_out;

    const int B = in_sizes[1];          // 262144

    // workspace layout
    int* perm = (int*)d_ws;                       // B ints
    int* eids = perm + B;                         // B ints
    int* hist = eids + B;                         // HB*NE ints
    int* base = hist + HB * NE;                   // HB*NE ints
    const size_t need = (size_t)(2 * B + 2 * HB * NE) * sizeof(int);

    if (ws_size >= need) {
        hist_kernel<<<HB, 256, 0, stream>>>(n, l, m, hist, B);
        scan_kernel<<<1, 64, 0, stream>>>(hist, base, HB);
        scatter_kernel<<<HB, 256, 0, stream>>>(n, l, m, base, perm, eids, B);
        wfc_kernel<<<B / THREADS, THREADS, 0, stream>>>(
            x, perm, eids, W0, b0, W1, b1, Wa, ba, Wb, bb, out);
    } else {
        // fallback: identity perm via tiny on-the-fly kernels is not worth it;
        // reuse scatter-free path: build perm=identity + eids inline.
        // (ws must hold at least 2*B ints; if not, nothing we can do fast.)
        hist_kernel<<<HB, 256, 0, stream>>>(n, l, m, (int*)d_ws, B); // placeholder to keep capture valid
    }
}

// Round 3
// 288.193 us; speedup vs baseline: 3.7854x; 3.7854x over previous
//
#include <hip/hip_runtime.h>
#include <math.h>

// WfcNN: B=262144.
//   h1 = tanh(x @ W0 + b0)            (B,128)
//   h2 = tanh(h1 @ W1 + b1)           (B,64)
//   g  = tanh(h2 . Wa[eid] + ba[eid]) (B,32)
//   psi= g . Wb[eid] + bb[eid]        (B,2) ; out = psi / sqrt(|psi|^2+1e-6)
//
// Round 3: one-expert-per-block + scalar-pipe weights.
// R2 lesson: launch_bounds(256,4) capped VGPR at 128 -> h1[128] spilled ->
// 3.9GB scratch traffic. Reverted to (256,2).
// R1 lesson: wave-uniform ds_read_b128 still costs the 1KB return path
// (~8cyc each, ~2048/thread) -> LDS-pipe floor ~150us. Fix: pad sorted
// buckets to block multiples so eid is BLOCK-uniform; all weight reads are
// then uniform -> s_load; inner loops are v_fmac_f32 (SGPR weight x VGPR h1).
// Zero LDS in the main kernel. fp32 throughout (tiny-|psi| normalization
// amplifies psi error ~2000x; bf16 anywhere would blow the 2e-2 threshold).

#define THREADS 256
#define NE 30
#define HB 64          // histogram/scatter blocks; B/HB samples each
#define MAXBLK 1056    // >= B/256 + 29 padded bucket blocks

__device__ __forceinline__ int expert_id(int nn, int ll, int mm) {
    return ((nn - 1) * nn * (2 * nn - 1)) / 6 + ll * ll + ll + mm;
}

__device__ __forceinline__ float fast_tanh(float v) {
    v = fminf(fmaxf(v, -15.0f), 15.0f);
    float e = __expf(2.0f * v);
    return (e - 1.0f) * __builtin_amdgcn_rcpf(e + 1.0f);
}

// ---- P1: per-block expert histogram ----
__global__ void hist_kernel(const int* __restrict__ nq, const int* __restrict__ lq,
                            const int* __restrict__ mq, int* __restrict__ hist, int B) {
    __shared__ int h[NE];
    const int tid = threadIdx.x;
    if (tid < NE) h[tid] = 0;
    __syncthreads();
    const int per = B / gridDim.x;
    const int base = blockIdx.x * per;
    for (int i = tid; i < per; i += blockDim.x)
        atomicAdd(&h[expert_id(nq[base + i], lq[base + i], mq[base + i])], 1);
    __syncthreads();
    if (tid < NE) hist[blockIdx.x * NE + tid] = h[tid];
}

// ---- P2: scan + scatter bases + block table + W1 transpose (1 block) ----
__global__ void plan_kernel(const int* __restrict__ hist, int* __restrict__ base,
                            int4* __restrict__ btab,
                            const float* __restrict__ W1, float* __restrict__ W1t) {
    __shared__ int sh[HB * NE];
    __shared__ int tot[NE], off[NE], sstart[NE], snb[NE];
    const int tid = threadIdx.x;
    for (int i = tid; i < HB * NE; i += blockDim.x) sh[i] = hist[i];
    // W1 (128,64) -> W1t (64,128)
    for (int i = tid; i < 128 * 64; i += blockDim.x) {
        int k = i >> 6, j = i & 63;
        W1t[j * 128 + k] = W1[i];
    }
    __syncthreads();
    if (tid < NE) {
        int s = 0;
        for (int b = 0; b < HB; ++b) s += sh[b * NE + tid];
        tot[tid] = s;
    }
    __syncthreads();
    if (tid == 0) {
        int acc = 0, slot = 0;
        for (int e = 0; e < NE; ++e) {
            off[e] = acc;
            int nb = (tot[e] + THREADS - 1) / THREADS;
            sstart[e] = slot; snb[e] = nb;
            slot += nb; acc += tot[e];
        }
    }
    __syncthreads();
    if (tid < NE) {                 // per-(histblock, expert) scatter cursors
        int acc = off[tid];
        for (int b = 0; b < HB; ++b) { base[b * NE + tid] = acc; acc += sh[b * NE + tid]; }
    }
    for (int e = 0; e < NE; ++e) {  // block table: one expert per compute block
        for (int j = tid; j < snb[e]; j += blockDim.x) {
            int4 bt;
            bt.x = e;
            bt.y = off[e] + j * THREADS;
            bt.z = min(THREADS, tot[e] - j * THREADS);
            bt.w = 0;
            btab[sstart[e] + j] = bt;
        }
    }
    __syncthreads();
    const int total = sstart[NE - 1] + snb[NE - 1];
    for (int s = total + tid; s < MAXBLK; s += blockDim.x) {
        int4 bt; bt.x = 0; bt.y = 0; bt.z = 0; bt.w = 0;
        btab[s] = bt;
    }
}

// ---- P3: scatter sample indices into sorted order ----
__global__ void scatter_kernel(const int* __restrict__ nq, const int* __restrict__ lq,
                               const int* __restrict__ mq, const int* __restrict__ base,
                               int* __restrict__ perm, int B) {
    __shared__ int cnt[NE];
    const int tid = threadIdx.x;
    if (tid < NE) cnt[tid] = base[blockIdx.x * NE + tid];
    __syncthreads();
    const int per = B / gridDim.x;
    const int blk = blockIdx.x * per;
    for (int i = tid; i < per; i += blockDim.x) {
        const int idx = blk + i;
        const int dst = atomicAdd(&cnt[expert_id(nq[idx], lq[idx], mq[idx])], 1);
        perm[dst] = idx;
    }
}

// ---- C: fused MLP; eid block-uniform -> all weights via scalar pipe ----
__global__ __launch_bounds__(THREADS, 2) void wfc_kernel(
    const float* __restrict__ x, const int* __restrict__ perm,
    const int4* __restrict__ btab,
    const float* __restrict__ W0, const float* __restrict__ b0,
    const float* __restrict__ W1t, const float* __restrict__ b1,
    const float* __restrict__ Wa, const float* __restrict__ ba,
    const float* __restrict__ Wb, const float* __restrict__ bb,
    float* __restrict__ out)
{
    const int4 bt = btab[blockIdx.x];       // uniform -> SGPRs
    const int cnt = bt.z;
    if (cnt == 0) return;
    const int eid = __builtin_amdgcn_readfirstlane(bt.x);
    const int tid = threadIdx.x;
    const bool valid = tid < cnt;
    const int idx = perm[bt.y + (valid ? tid : 0)];

    const float x0 = x[idx * 3 + 0];
    const float x1 = x[idx * 3 + 1];
    const float x2 = x[idx * 3 + 2];

    // layer 1: weights uniform -> s_load; h1 in VGPRs (static indices)
    float h1[128];
#pragma unroll
    for (int i = 0; i < 128; ++i)
        h1[i] = fast_tanh(fmaf(x0, W0[i], fmaf(x1, W0[128 + i], fmaf(x2, W0[256 + i], b0[i]))));

    float g[32];
    const float* bae = ba + (eid << 5);
#pragma unroll
    for (int h = 0; h < 32; ++h) g[h] = bae[h];

    // fused layer2 + expert-A; all weight reads uniform (scalar pipe)
    const float* wae = Wa + eid * 2048;
#pragma unroll 2
    for (int d = 0; d < 64; ++d) {
        const float* wrow = W1t + d * 128;
        float a0 = 0.f, a1 = 0.f, a2 = 0.f, a3 = 0.f;
#pragma unroll
        for (int k = 0; k < 128; k += 4) {
            a0 = fmaf(h1[k + 0], wrow[k + 0], a0);
            a1 = fmaf(h1[k + 1], wrow[k + 1], a1);
            a2 = fmaf(h1[k + 2], wrow[k + 2], a2);
            a3 = fmaf(h1[k + 3], wrow[k + 3], a3);
        }
        const float hd = fast_tanh(b1[d] + ((a0 + a1) + (a2 + a3)));
        const float* war = wae + d * 32;
#pragma unroll
        for (int h = 0; h < 32; ++h) g[h] = fmaf(hd, war[h], g[h]);
    }

#pragma unroll
    for (int h = 0; h < 32; ++h) g[h] = fast_tanh(g[h]);

    const float* wbe = Wb + (eid << 6);
    float p0 = bb[2 * eid], p1 = bb[2 * eid + 1];
#pragma unroll
    for (int h = 0; h < 32; ++h) {
        p0 = fmaf(g[h], wbe[2 * h + 0], p0);
        p1 = fmaf(g[h], wbe[2 * h + 1], p1);
    }

    const float s = fmaf(p0, p0, fmaf(p1, p1, 1e-6f));
    const float inv = 1.0f / sqrtf(s);
    if (valid) {
        float2 o; o.x = p0 * inv; o.y = p1 * inv;
        ((float2*)out)[idx] = o;
    }
}

extern "C" void kernel_launch(void* const* d_in, const int* in_sizes, int n_in,
                              void* d_out, int out_size, void* d_ws, size_t ws_size,
                              hipStream_t stream) {
    const float* x  = (const float*)d_in[0];
    const int*   n  = (const int*)d_in[1];
    const int*   l  = (const int*)d_in[2];
    const int*   m  = (const int*)d_in[3];
    const float* W0 = (const float*)d_in[4];
    const float* b0 = (const float*)d_in[5];
    const float* W1 = (const float*)d_in[6];
    const float* b1 = (const float*)d_in[7];
    const float* Wa = (const float*)d_in[8];
    const float* ba = (const float*)d_in[9];
    const float* Wb = (const float*)d_in[10];
    const float* bb = (const float*)d_in[11];
    float* out = (float*)d_out;

    const int B = in_sizes[1];   // 262144

    // workspace layout (all 16B aligned)
    int*   perm = (int*)d_ws;                    // B ints
    int4*  btab = (int4*)(perm + B);             // MAXBLK int4
    int*   hist = (int*)(btab + MAXBLK);         // HB*NE
    int*   base = hist + HB * NE;                // HB*NE
    float* W1t  = (float*)(base + HB * NE);      // 64*128 floats

    hist_kernel<<<HB, 256, 0, stream>>>(n, l, m, hist, B);
    plan_kernel<<<1, 256, 0, stream>>>(hist, base, btab, W1, W1t);
    scatter_kernel<<<HB, 256, 0, stream>>>(n, l, m, base, perm, B);
    wfc_kernel<<<MAXBLK, THREADS, 0, stream>>>(
        x, perm, btab, W0, b0, W1t, b1, Wa, ba, Wb, bb, out);
}

// Round 4
// 226.210 us; speedup vs baseline: 4.8226x; 1.2740x over previous
//
#include <hip/hip_runtime.h>
#include <math.h>

// WfcNN: B=262144.
//   h1 = tanh(x @ W0 + b0)            (B,128)
//   h2 = tanh(h1 @ W1 + b1)           (B,64)
//   g  = tanh(h2 . Wa[eid] + ba[eid]) (B,32)
//   psi= g . Wb[eid] + bb[eid]        (B,2) ; out = psi / sqrt(|psi|^2+1e-6)
//
// Round 4: loop-interchanged main kernel.
// R3 lesson: h1[128] got shadowed into AGPRs -> unified regfile ~254/wave ->
// 2 waves/SIMD -> s_load latency exposed (VALUBusy 28%). Interchange layer 2:
//   for k: hk = tanh(x . W0[:,k] + b0[k]);  acc[d] += hk * W1[k][d]
// h1 storage eliminated; W1 used in native (128,64) layout (no transpose);
// peak regs ~120 -> 4 waves/SIMD. All weights stay on the scalar pipe
// (eid block-uniform after padded counting sort). fp32 throughout (the
// normalize amplifies psi error by up to ~1/2.6e-4; bf16 would fail).

#define THREADS 256
#define NE 30
#define HB 128         // histogram/scatter blocks; B/HB samples each
#define MAXBLK 1056    // >= B/256 + 29 padded bucket blocks

__device__ __forceinline__ int expert_id(int nn, int ll, int mm) {
    return ((nn - 1) * nn * (2 * nn - 1)) / 6 + ll * ll + ll + mm;
}

__device__ __forceinline__ float fast_tanh(float v) {
    v = fminf(fmaxf(v, -15.0f), 15.0f);
    float e = __expf(2.0f * v);
    return (e - 1.0f) * __builtin_amdgcn_rcpf(e + 1.0f);
}

// ---- P1: per-block expert histogram ----
__global__ void hist_kernel(const int* __restrict__ nq, const int* __restrict__ lq,
                            const int* __restrict__ mq, int* __restrict__ hist, int B) {
    __shared__ int h[NE];
    const int tid = threadIdx.x;
    if (tid < NE) h[tid] = 0;
    __syncthreads();
    const int per = B / gridDim.x;
    const int base = blockIdx.x * per;
    for (int i = tid; i < per; i += blockDim.x)
        atomicAdd(&h[expert_id(nq[base + i], lq[base + i], mq[base + i])], 1);
    __syncthreads();
    if (tid < NE) hist[blockIdx.x * NE + tid] = h[tid];
}

// ---- P2: scan + scatter bases + block table (1 block) ----
__global__ void plan_kernel(const int* __restrict__ hist, int* __restrict__ base,
                            int4* __restrict__ btab) {
    __shared__ int sh[HB * NE];
    __shared__ int tot[NE], off[NE], sstart[NE], snb[NE];
    const int tid = threadIdx.x;
    for (int i = tid; i < HB * NE; i += blockDim.x) sh[i] = hist[i];
    __syncthreads();
    if (tid < NE) {
        int s = 0;
        for (int b = 0; b < HB; ++b) s += sh[b * NE + tid];
        tot[tid] = s;
    }
    __syncthreads();
    if (tid == 0) {
        int acc = 0, slot = 0;
        for (int e = 0; e < NE; ++e) {
            off[e] = acc;
            int nb = (tot[e] + THREADS - 1) / THREADS;
            sstart[e] = slot; snb[e] = nb;
            slot += nb; acc += tot[e];
        }
    }
    __syncthreads();
    if (tid < NE) {                 // per-(histblock, expert) scatter cursors
        int acc = off[tid];
        for (int b = 0; b < HB; ++b) { base[b * NE + tid] = acc; acc += sh[b * NE + tid]; }
    }
    for (int e = 0; e < NE; ++e) {  // block table: one expert per compute block
        for (int j = tid; j < snb[e]; j += blockDim.x) {
            int4 bt;
            bt.x = e;
            bt.y = off[e] + j * THREADS;
            bt.z = min(THREADS, tot[e] - j * THREADS);
            bt.w = 0;
            btab[sstart[e] + j] = bt;
        }
    }
    __syncthreads();
    const int total = sstart[NE - 1] + snb[NE - 1];
    for (int s = total + tid; s < MAXBLK; s += blockDim.x) {
        int4 bt; bt.x = 0; bt.y = 0; bt.z = 0; bt.w = 0;
        btab[s] = bt;
    }
}

// ---- P3: scatter sample indices into sorted order ----
__global__ void scatter_kernel(const int* __restrict__ nq, const int* __restrict__ lq,
                               const int* __restrict__ mq, const int* __restrict__ base,
                               int* __restrict__ perm, int B) {
    __shared__ int cnt[NE];
    const int tid = threadIdx.x;
    if (tid < NE) cnt[tid] = base[blockIdx.x * NE + tid];
    __syncthreads();
    const int per = B / gridDim.x;
    const int blk = blockIdx.x * per;
    for (int i = tid; i < per; i += blockDim.x) {
        const int idx = blk + i;
        const int dst = atomicAdd(&cnt[expert_id(nq[idx], lq[idx], mq[idx])], 1);
        perm[dst] = idx;
    }
}

// ---- C: fused MLP, loop-interchanged; all weights via scalar pipe ----
__global__ __launch_bounds__(THREADS, 3) void wfc_kernel(
    const float* __restrict__ x, const int* __restrict__ perm,
    const int4* __restrict__ btab,
    const float* __restrict__ W0, const float* __restrict__ b0,
    const float* __restrict__ W1, const float* __restrict__ b1,
    const float* __restrict__ Wa, const float* __restrict__ ba,
    const float* __restrict__ Wb, const float* __restrict__ bb,
    float* __restrict__ out)
{
    const int4 bt = btab[blockIdx.x];       // uniform -> SGPRs
    if (bt.z == 0) return;
    const int eid = __builtin_amdgcn_readfirstlane(bt.x);
    const int tid = threadIdx.x;
    const bool valid = tid < bt.z;
    const int idx = perm[bt.y + (valid ? tid : 0)];

    const float x0 = x[idx * 3 + 0];
    const float x1 = x[idx * 3 + 1];
    const float x2 = x[idx * 3 + 2];

    // acc[d] accumulates layer-2 pre-activation; init with b1 (uniform loads)
    float acc[64];
#pragma unroll
    for (int d = 0; d < 64; ++d) acc[d] = b1[d];

    // phase 1: rank-1 updates. hk computed inline (no h1 array).
    // W1 row k (64 floats, contiguous) arrives as 4x s_load_dwordx16.
    for (int k = 0; k < 128; ++k) {
        const float pre = fmaf(x0, W0[k], fmaf(x1, W0[128 + k], fmaf(x2, W0[256 + k], b0[k])));
        const float hk = fast_tanh(pre);
        const float* __restrict__ wrow = W1 + k * 64;
#pragma unroll
        for (int d = 0; d < 64; ++d) acc[d] = fmaf(hk, wrow[d], acc[d]);
    }

    // phase 2: h2 -> expert-A accumulation (fully unrolled: static acc index)
    float g[32];
    const float* __restrict__ bae = ba + (eid << 5);
#pragma unroll
    for (int h = 0; h < 32; ++h) g[h] = bae[h];

    const float* __restrict__ wae = Wa + eid * 2048;
#pragma unroll
    for (int d = 0; d < 64; ++d) {
        const float hd = fast_tanh(acc[d]);
        const float* __restrict__ war = wae + d * 32;
#pragma unroll
        for (int h = 0; h < 32; ++h) g[h] = fmaf(hd, war[h], g[h]);
    }

#pragma unroll
    for (int h = 0; h < 32; ++h) g[h] = fast_tanh(g[h]);

    // expert-B
    const float* __restrict__ wbe = Wb + (eid << 6);
    float p0 = bb[2 * eid], p1 = bb[2 * eid + 1];
#pragma unroll
    for (int h = 0; h < 32; ++h) {
        p0 = fmaf(g[h], wbe[2 * h + 0], p0);
        p1 = fmaf(g[h], wbe[2 * h + 1], p1);
    }

    const float s = fmaf(p0, p0, fmaf(p1, p1, 1e-6f));
    const float inv = 1.0f / sqrtf(s);
    if (valid) {
        float2 o; o.x = p0 * inv; o.y = p1 * inv;
        ((float2*)out)[idx] = o;
    }
}

extern "C" void kernel_launch(void* const* d_in, const int* in_sizes, int n_in,
                              void* d_out, int out_size, void* d_ws, size_t ws_size,
                              hipStream_t stream) {
    const float* x  = (const float*)d_in[0];
    const int*   n  = (const int*)d_in[1];
    const int*   l  = (const int*)d_in[2];
    const int*   m  = (const int*)d_in[3];
    const float* W0 = (const float*)d_in[4];
    const float* b0 = (const float*)d_in[5];
    const float* W1 = (const float*)d_in[6];
    const float* b1 = (const float*)d_in[7];
    const float* Wa = (const float*)d_in[8];
    const float* ba = (const float*)d_in[9];
    const float* Wb = (const float*)d_in[10];
    const float* bb = (const float*)d_in[11];
    float* out = (float*)d_out;

    const int B = in_sizes[1];   // 262144

    // workspace layout (16B aligned pieces)
    int*  perm = (int*)d_ws;                    // B ints
    int4* btab = (int4*)(perm + B);             // MAXBLK int4
    int*  hist = (int*)(btab + MAXBLK);         // HB*NE
    int*  base = hist + HB * NE;                // HB*NE

    hist_kernel<<<HB, 256, 0, stream>>>(n, l, m, hist, B);
    plan_kernel<<<1, 256, 0, stream>>>(hist, base, btab);
    scatter_kernel<<<HB, 256, 0, stream>>>(n, l, m, base, perm, B);
    wfc_kernel<<<MAXBLK, THREADS, 0, stream>>>(
        x, perm, btab, W0, b0, W1, b1, Wa, ba, Wb, bb, out);
}

// Round 5
// 188.112 us; speedup vs baseline: 5.7993x; 1.2025x over previous
//
#include <hip/hip_runtime.h>
#include <math.h>

// WfcNN: B=262144.
//   h1 = tanh(x @ W0 + b0)            (B,128)
//   h2 = tanh(h1 @ W1 + b1)           (B,64)
//   g  = tanh(h2 . Wa[eid] + ba[eid]) (B,32)
//   psi= g . Wb[eid] + bb[eid]        (B,2) ; out = psi / sqrt(|psi|^2+1e-6)
//
// Round 5: layer-2 GEMM on MFMA with 4-pass split-bf16 (h=hi+lo, W1=hi+lo;
// acc lo*lo + lo*hi + hi*lo + hi*hi in fp32 C) -- ~2^-17 relative element
// error, ~fp32-class after the 1000x normalize amplification. Removes 8192
// of 10.8k per-thread FMAs (R4 was VALU+SMEM-latency bound at 42% VALUBusy).
// Expert-A stays on the scalar pipe (block-uniform eid after counting sort).
// LDS ~41.5KB -> 3 blocks/CU. Fragment layouts per verified guide:
//   A[m=lane&15][k=quad*8+j], B[k=quad*8+j][n=lane&15],
//   C[row=quad*4+reg][col=lane&15].

#define THREADS 256
#define NE 30
#define HB 128
#define MAXBLK 1056
#define SA 258            // sA row stride (u32) for [k][sample]
#define SW 33             // sW1c row stride (u32) for [n][k-chunk]
#define SH 17             // h2 stage row stride (f32)

typedef short bf16x8 __attribute__((ext_vector_type(8)));
typedef float f32x4 __attribute__((ext_vector_type(4)));

__device__ __forceinline__ int expert_id(int nn, int ll, int mm) {
    return ((nn - 1) * nn * (2 * nn - 1)) / 6 + ll * ll + ll + mm;
}

__device__ __forceinline__ float fast_tanh(float v) {
    v = fminf(fmaxf(v, -15.0f), 15.0f);
    float e = __expf(2.0f * v);
    return (e - 1.0f) * __builtin_amdgcn_rcpf(e + 1.0f);
}

__device__ __forceinline__ unsigned int f2b(float f) {   // f32 -> bf16 RNE
    unsigned int u = __float_as_uint(f);
    return (u + 0x7fffu + ((u >> 16) & 1u)) >> 16;
}
__device__ __forceinline__ float b2f(unsigned int b) {
    return __uint_as_float(b << 16);
}

union U8 { unsigned int u[4]; bf16x8 v; };
__device__ __forceinline__ void unpack8(const unsigned int* w, bf16x8& hi, bf16x8& lo) {
    U8 H, L;
#pragma unroll
    for (int i = 0; i < 4; ++i) {
        H.u[i] = (w[2 * i + 1] << 16) | (w[2 * i] & 0xffffu);
        L.u[i] = (w[2 * i + 1] & 0xffff0000u) | (w[2 * i] >> 16);
    }
    hi = H.v; lo = L.v;
}

// ---- P1: per-block expert histogram ----
__global__ void hist_kernel(const int* __restrict__ nq, const int* __restrict__ lq,
                            const int* __restrict__ mq, int* __restrict__ hist, int B) {
    __shared__ int h[NE];
    const int tid = threadIdx.x;
    if (tid < NE) h[tid] = 0;
    __syncthreads();
    const int per = B / gridDim.x;
    const int base = blockIdx.x * per;
    for (int i = tid; i < per; i += blockDim.x)
        atomicAdd(&h[expert_id(nq[base + i], lq[base + i], mq[base + i])], 1);
    __syncthreads();
    if (tid < NE) hist[blockIdx.x * NE + tid] = h[tid];
}

// ---- P2: scan + scatter bases + block table + W1 split-pack (1 block) ----
__global__ void plan_kernel(const int* __restrict__ hist, int* __restrict__ base,
                            int4* __restrict__ btab,
                            const float* __restrict__ W1, unsigned int* __restrict__ W1pk) {
    __shared__ int sh[HB * NE];
    __shared__ int tot[NE], off[NE], sstart[NE], snb[NE];
    const int tid = threadIdx.x;
    for (int i = tid; i < HB * NE; i += blockDim.x) sh[i] = hist[i];
    // W1 (128,64) row-major -> W1pk[n][k] packed (lo16<<16)|hi16
    for (int i = tid; i < 128 * 64; i += blockDim.x) {
        int k = i >> 6, n = i & 63;
        float w = W1[i];
        unsigned int hb = f2b(w);
        unsigned int lb = f2b(w - b2f(hb));
        W1pk[n * 128 + k] = (lb << 16) | hb;
    }
    __syncthreads();
    if (tid < NE) {
        int s = 0;
        for (int b = 0; b < HB; ++b) s += sh[b * NE + tid];
        tot[tid] = s;
    }
    __syncthreads();
    if (tid == 0) {
        int acc = 0, slot = 0;
        for (int e = 0; e < NE; ++e) {
            off[e] = acc;
            int nb = (tot[e] + THREADS - 1) / THREADS;
            sstart[e] = slot; snb[e] = nb;
            slot += nb; acc += tot[e];
        }
    }
    __syncthreads();
    if (tid < NE) {
        int acc = off[tid];
        for (int b = 0; b < HB; ++b) { base[b * NE + tid] = acc; acc += sh[b * NE + tid]; }
    }
    for (int e = 0; e < NE; ++e) {
        for (int j = tid; j < snb[e]; j += blockDim.x) {
            int4 bt;
            bt.x = e;
            bt.y = off[e] + j * THREADS;
            bt.z = min(THREADS, tot[e] - j * THREADS);
            bt.w = 0;
            btab[sstart[e] + j] = bt;
        }
    }
    __syncthreads();
    const int total = sstart[NE - 1] + snb[NE - 1];
    for (int s = total + tid; s < MAXBLK; s += blockDim.x) {
        int4 bt; bt.x = 0; bt.y = 0; bt.z = 0; bt.w = 0;
        btab[s] = bt;
    }
}

// ---- P3: scatter sample indices into sorted order ----
__global__ void scatter_kernel(const int* __restrict__ nq, const int* __restrict__ lq,
                               const int* __restrict__ mq, const int* __restrict__ base,
                               int* __restrict__ perm, int B) {
    __shared__ int cnt[NE];
    const int tid = threadIdx.x;
    if (tid < NE) cnt[tid] = base[blockIdx.x * NE + tid];
    __syncthreads();
    const int per = B / gridDim.x;
    const int blk = blockIdx.x * per;
    for (int i = tid; i < per; i += blockDim.x) {
        const int idx = blk + i;
        const int dst = atomicAdd(&cnt[expert_id(nq[idx], lq[idx], mq[idx])], 1);
        perm[dst] = idx;
    }
}

// ---- C: fused MLP; layer2 on MFMA (split-bf16 x4), rest VALU/scalar ----
__global__ __launch_bounds__(THREADS, 3) void wfc_kernel(
    const float* __restrict__ x, const int* __restrict__ perm,
    const int4* __restrict__ btab,
    const float* __restrict__ W0, const float* __restrict__ b0,
    const unsigned int* __restrict__ W1pk, const float* __restrict__ b1,
    const float* __restrict__ Wa, const float* __restrict__ ba,
    const float* __restrict__ Wb, const float* __restrict__ bb,
    float* __restrict__ out)
{
    __shared__ unsigned int sA[32 * SA];     // h chunk, [k][sample] packed lo|hi  (33,024 B)
    __shared__ unsigned int sW1c[64 * SW];   // W1 chunk, [n][k] packed            ( 8,448 B)

    const int4 bt = btab[blockIdx.x];        // block-uniform
    if (bt.z == 0) return;
    const int eid = __builtin_amdgcn_readfirstlane(bt.x);
    const int tid = threadIdx.x;
    const bool valid = tid < bt.z;
    const int idx = perm[bt.y + (valid ? tid : 0)];

    const int lane = tid & 63;
    const int wv   = tid >> 6;     // wave 0..3 -> rows [64*wv, 64*wv+64)
    const int qd   = lane >> 4;    // quad
    const int l16  = lane & 15;

    const float x0 = x[idx * 3 + 0];
    const float x1 = x[idx * 3 + 1];
    const float x2 = x[idx * 3 + 2];

    // acc init with b1 (C layout: col = lane&15 = n)
    f32x4 acc[4][4];               // [mtile][ntile]
#pragma unroll
    for (int nt = 0; nt < 4; ++nt) {
        const float bv = b1[nt * 16 + l16];
#pragma unroll
        for (int mt = 0; mt < 4; ++mt) {
            f32x4 c; c[0] = bv; c[1] = bv; c[2] = bv; c[3] = bv;
            acc[mt][nt] = c;
        }
    }

    // ---- K loop: 4 chunks of 32 ----
    for (int c = 0; c < 4; ++c) {
        if (c) __syncthreads();             // prior chunk's LDS reads done
        // stage W1 chunk: [n][k] packed, 2048 words
        for (int i = tid; i < 64 * 32; i += THREADS) {
            int n = i >> 5, kk = i & 31;
            sW1c[n * SW + kk] = W1pk[n * 128 + c * 32 + kk];
        }
        // compute h for 32 k's, split, pack, write [k][tid]
#pragma unroll
        for (int kk = 0; kk < 32; ++kk) {
            const int k = c * 32 + kk;
            const float pre = fmaf(x0, W0[k], fmaf(x1, W0[128 + k], fmaf(x2, W0[256 + k], b0[k])));
            const float h = fast_tanh(pre);
            const unsigned int hb = f2b(h);
            const unsigned int lb = f2b(h - b2f(hb));
            sA[kk * SA + tid] = (lb << 16) | hb;
        }
        __syncthreads();

        // B fragments for this chunk (4 ntiles, hi/lo)
        bf16x8 Bhi[4], Blo[4];
#pragma unroll
        for (int nt = 0; nt < 4; ++nt) {
            unsigned int w[8];
#pragma unroll
            for (int j = 0; j < 8; ++j)
                w[j] = sW1c[(nt * 16 + l16) * SW + qd * 8 + j];
            unpack8(w, Bhi[nt], Blo[nt]);
        }
        // A fragments per mtile, 4-pass MFMA
#pragma unroll
        for (int mt = 0; mt < 4; ++mt) {
            unsigned int a[8];
            const int mrow = wv * 64 + mt * 16 + l16;
#pragma unroll
            for (int j = 0; j < 8; ++j)
                a[j] = sA[(qd * 8 + j) * SA + mrow];
            bf16x8 Ahi, Alo;
            unpack8(a, Ahi, Alo);
#pragma unroll
            for (int nt = 0; nt < 4; ++nt) {
                acc[mt][nt] = __builtin_amdgcn_mfma_f32_16x16x32_bf16(Alo, Blo[nt], acc[mt][nt], 0, 0, 0);
                acc[mt][nt] = __builtin_amdgcn_mfma_f32_16x16x32_bf16(Alo, Bhi[nt], acc[mt][nt], 0, 0, 0);
                acc[mt][nt] = __builtin_amdgcn_mfma_f32_16x16x32_bf16(Ahi, Blo[nt], acc[mt][nt], 0, 0, 0);
                acc[mt][nt] = __builtin_amdgcn_mfma_f32_16x16x32_bf16(Ahi, Bhi[nt], acc[mt][nt], 0, 0, 0);
            }
        }
    }

    // ---- expert-A: stage h2 per ntile through LDS, accumulate g on VALU ----
    float g[32];
    const float* __restrict__ bae = ba + (eid << 5);
#pragma unroll
    for (int h = 0; h < 32; ++h) g[h] = bae[h];

    float* h2s = (float*)sA;                 // reuse region (17,408 B needed)
    const float* __restrict__ wae = Wa + eid * 2048;
#pragma unroll
    for (int nt = 0; nt < 4; ++nt) {
        __syncthreads();                     // previous nt consumed / MFMA reads done
#pragma unroll
        for (int mt = 0; mt < 4; ++mt) {
#pragma unroll
            for (int r = 0; r < 4; ++r) {
                const int mrow = wv * 64 + mt * 16 + qd * 4 + r;   // C layout row
                h2s[mrow * SH + l16] = acc[mt][nt][r];
            }
        }
        __syncthreads();
        float hd[16];
#pragma unroll
        for (int i = 0; i < 16; ++i) hd[i] = fast_tanh(h2s[tid * SH + i]);
        const float* __restrict__ war = wae + (nt * 16) * 32;
#pragma unroll
        for (int dd = 0; dd < 16; ++dd) {
#pragma unroll
            for (int h = 0; h < 32; ++h)
                g[h] = fmaf(hd[dd], war[dd * 32 + h], g[h]);
        }
    }

#pragma unroll
    for (int h = 0; h < 32; ++h) g[h] = fast_tanh(g[h]);

    // ---- expert-B + normalize ----
    const float* __restrict__ wbe = Wb + (eid << 6);
    float p0 = bb[2 * eid], p1 = bb[2 * eid + 1];
#pragma unroll
    for (int h = 0; h < 32; ++h) {
        p0 = fmaf(g[h], wbe[2 * h + 0], p0);
        p1 = fmaf(g[h], wbe[2 * h + 1], p1);
    }
    const float s = fmaf(p0, p0, fmaf(p1, p1, 1e-6f));
    const float inv = 1.0f / sqrtf(s);
    if (valid) {
        float2 o; o.x = p0 * inv; o.y = p1 * inv;
        ((float2*)out)[idx] = o;
    }
}

extern "C" void kernel_launch(void* const* d_in, const int* in_sizes, int n_in,
                              void* d_out, int out_size, void* d_ws, size_t ws_size,
                              hipStream_t stream) {
    const float* x  = (const float*)d_in[0];
    const int*   n  = (const int*)d_in[1];
    const int*   l  = (const int*)d_in[2];
    const int*   m  = (const int*)d_in[3];
    const float* W0 = (const float*)d_in[4];
    const float* b0 = (const float*)d_in[5];
    const float* W1 = (const float*)d_in[6];
    const float* b1 = (const float*)d_in[7];
    const float* Wa = (const float*)d_in[8];
    const float* ba = (const float*)d_in[9];
    const float* Wb = (const float*)d_in[10];
    const float* bb = (const float*)d_in[11];
    float* out = (float*)d_out;

    const int B = in_sizes[1];   // 262144

    // workspace layout (16B-aligned pieces)
    int*          perm = (int*)d_ws;                  // B ints
    int4*         btab = (int4*)(perm + B);           // MAXBLK int4
    int*          hist = (int*)(btab + MAXBLK);       // HB*NE
    int*          base = hist + HB * NE;              // HB*NE
    unsigned int* W1pk = (unsigned int*)(base + HB * NE);  // 64*128 u32

    hist_kernel<<<HB, 256, 0, stream>>>(n, l, m, hist, B);
    plan_kernel<<<1, 256, 0, stream>>>(hist, base, btab, W1, W1pk);
    scatter_kernel<<<HB, 256, 0, stream>>>(n, l, m, base, perm, B);
    wfc_kernel<<<MAXBLK, THREADS, 0, stream>>>(
        x, perm, btab, W0, b0, W1pk, b1, Wa, ba, Wb, bb, out);
}

// Round 6
// 153.763 us; speedup vs baseline: 7.0948x; 1.2234x over previous
//
#include <hip/hip_runtime.h>
#include <math.h>

// WfcNN: B=262144.
//   h1 = tanh(x @ W0 + b0)            (B,128)
//   h2 = tanh(h1 @ W1 + b1)           (B,64)
//   g  = tanh(h2 . Wa[eid] + ba[eid]) (B,32)
//   psi= g . Wb[eid] + bb[eid]        (B,2) ; out = psi / sqrt(|psi|^2+1e-6)
//
// Round 6: both GEMMs (layer2 AND expert-A) on MFMA with 3-pass split-bf16
// (hh + hl + lh; lo*lo ~2^-18 rel, same order as split error -> dropped).
// h2 round-trips C-layout -> [d][sample] LDS (same staging/frag pattern that
// validated in R5). g round-trips to [sample][h] LDS (stride 36, bank-even);
// expert-B per-thread on VALU. W1/Wa pre-split-packed in prep (folded into
// hist's grid); W1 B-frags read straight from global (L2 broadcast) -- no LDS
// restage. fp32-class precision maintained (normalize amplifies ~1000x).

#define THREADS 256
#define NE 30
#define HB 128
#define MAXBLK 1056
#define SA 259            // u32 row stride for [k][sample] staging (odd -> 2-way max)
#define SG 36             // f32 row stride for [sample][h] g staging

typedef short bf16x8 __attribute__((ext_vector_type(8)));
typedef float f32x4 __attribute__((ext_vector_type(4)));

__device__ __forceinline__ int expert_id(int nn, int ll, int mm) {
    return ((nn - 1) * nn * (2 * nn - 1)) / 6 + ll * ll + ll + mm;
}

// tanh(v) = 1 - 2/(exp2(2*log2e*v)+1). Saturates correctly at +/-inf of the
// exp (exp2->inf => 1; exp2->0 => -1), no clamp needed. 5 VALU ops.
__device__ __forceinline__ float fast_tanh(float v) {
    float e = __builtin_exp2f(v * 2.885390082f);
    return fmaf(-2.0f, __builtin_amdgcn_rcpf(e + 1.0f), 1.0f);
}

__device__ __forceinline__ unsigned int f2b(float f) {   // f32 -> bf16 RNE
    unsigned int u = __float_as_uint(f);
    return (u + 0x7fffu + ((u >> 16) & 1u)) >> 16;
}
__device__ __forceinline__ float b2f(unsigned int b) {
    return __uint_as_float(b << 16);
}
__device__ __forceinline__ unsigned int packsplit(float v) {
    unsigned int hb = f2b(v);
    unsigned int lb = f2b(v - b2f(hb));
    return (lb << 16) | hb;
}

union U8 { unsigned int u[4]; bf16x8 v; };
__device__ __forceinline__ void unpack8(const unsigned int* w, bf16x8& hi, bf16x8& lo) {
    U8 H, L;
#pragma unroll
    for (int i = 0; i < 4; ++i) {
        H.u[i] = (w[2 * i + 1] << 16) | (w[2 * i] & 0xffffu);
        L.u[i] = (w[2 * i + 1] & 0xffff0000u) | (w[2 * i] >> 16);
    }
    hi = H.v; lo = L.v;
}

// ---- P1: per-block expert histogram + eid cache + weight split-packing ----
__global__ void hist_pack_kernel(const int* __restrict__ nq, const int* __restrict__ lq,
                                 const int* __restrict__ mq, int* __restrict__ hist,
                                 int* __restrict__ eids,
                                 const float* __restrict__ W1, unsigned int* __restrict__ W1pk,
                                 const float* __restrict__ Wa, unsigned int* __restrict__ Wapk,
                                 int B) {
    const int tid = threadIdx.x;
    const int bx = blockIdx.x;
    if (bx < HB) {
        __shared__ int h[NE];
        if (tid < NE) h[tid] = 0;
        __syncthreads();
        const int per = B / HB, base = bx * per;
        for (int i = tid; i < per; i += blockDim.x) {
            const int e = expert_id(nq[base + i], lq[base + i], mq[base + i]);
            eids[base + i] = e;
            atomicAdd(&h[e], 1);
        }
        __syncthreads();
        if (tid < NE) hist[bx * NE + tid] = h[tid];
    } else if (bx < HB + 4) {
        // W1 (128,64) row-major -> W1pk[n][k] packed, segment of 2048
        const int seg = bx - HB;
        for (int i = seg * 2048 + tid; i < (seg + 1) * 2048; i += blockDim.x) {
            const int n = i >> 7, k = i & 127;
            W1pk[i] = packsplit(W1[k * 64 + n]);
        }
    } else {
        // Wa[e] (64,32) -> Wapk[e][h][d] packed
        const int e = bx - HB - 4;
        for (int i = tid; i < 2048; i += blockDim.x) {
            const int hh = i >> 6, d = i & 63;
            Wapk[e * 2048 + i] = packsplit(Wa[e * 2048 + d * 32 + hh]);
        }
    }
}

// ---- P2: scan + scatter bases + block table (1 block) ----
__global__ void plan_kernel(const int* __restrict__ hist, int* __restrict__ base,
                            int4* __restrict__ btab) {
    __shared__ int sh[HB * NE];
    __shared__ int tot[NE], off[NE], sstart[NE], snb[NE];
    const int tid = threadIdx.x;
    for (int i = tid; i < HB * NE; i += blockDim.x) sh[i] = hist[i];
    __syncthreads();
    if (tid < NE) {
        int s = 0;
        for (int b = 0; b < HB; ++b) s += sh[b * NE + tid];
        tot[tid] = s;
    }
    __syncthreads();
    if (tid == 0) {
        int acc = 0, slot = 0;
        for (int e = 0; e < NE; ++e) {
            off[e] = acc;
            int nb = (tot[e] + THREADS - 1) / THREADS;
            sstart[e] = slot; snb[e] = nb;
            slot += nb; acc += tot[e];
        }
    }
    __syncthreads();
    if (tid < NE) {
        int acc = off[tid];
        for (int b = 0; b < HB; ++b) { base[b * NE + tid] = acc; acc += sh[b * NE + tid]; }
    }
    for (int e = 0; e < NE; ++e) {
        for (int j = tid; j < snb[e]; j += blockDim.x) {
            int4 bt;
            bt.x = e;
            bt.y = off[e] + j * THREADS;
            bt.z = min(THREADS, tot[e] - j * THREADS);
            bt.w = 0;
            btab[sstart[e] + j] = bt;
        }
    }
    __syncthreads();
    const int total = sstart[NE - 1] + snb[NE - 1];
    for (int s = total + tid; s < MAXBLK; s += blockDim.x) {
        int4 bt; bt.x = 0; bt.y = 0; bt.z = 0; bt.w = 0;
        btab[s] = bt;
    }
}

// ---- P3: scatter sample indices into sorted order (uses cached eids) ----
__global__ void scatter_kernel(const int* __restrict__ eids, const int* __restrict__ base,
                               int* __restrict__ perm, int B) {
    __shared__ int cnt[NE];
    const int tid = threadIdx.x;
    if (tid < NE) cnt[tid] = base[blockIdx.x * NE + tid];
    __syncthreads();
    const int per = B / gridDim.x;
    const int blk = blockIdx.x * per;
    for (int i = tid; i < per; i += blockDim.x) {
        const int idx = blk + i;
        const int dst = atomicAdd(&cnt[eids[idx]], 1);
        perm[dst] = idx;
    }
}

// ---- C: fused MLP; layer2 + expert-A on MFMA (3-pass split-bf16) ----
__global__ __launch_bounds__(THREADS, 3) void wfc_kernel(
    const float* __restrict__ x, const int* __restrict__ perm,
    const int4* __restrict__ btab,
    const float* __restrict__ W0, const float* __restrict__ b0,
    const unsigned int* __restrict__ W1pk, const float* __restrict__ b1,
    const unsigned int* __restrict__ Wapk, const float* __restrict__ ba,
    const float* __restrict__ Wb, const float* __restrict__ bb,
    float* __restrict__ out)
{
    __shared__ unsigned int sbuf[9216];      // 36,864 B: [d][sample] stage / g stage

    const int4 bt = btab[blockIdx.x];        // block-uniform
    if (bt.z == 0) return;
    const int eid = __builtin_amdgcn_readfirstlane(bt.x);
    const int tid = threadIdx.x;
    const bool valid = tid < bt.z;
    const int idx = perm[bt.y + (valid ? tid : 0)];

    const int lane = tid & 63;
    const int wv   = tid >> 6;
    const int qd   = lane >> 4;
    const int l16  = lane & 15;

    const float x0 = x[idx * 3 + 0];
    const float x1 = x[idx * 3 + 1];
    const float x2 = x[idx * 3 + 2];

    // ---- layer 2 accumulators, init b1 (C layout: col = l16) ----
    f32x4 acc[4][4];                         // [mtile][ntile]
#pragma unroll
    for (int nt = 0; nt < 4; ++nt) {
        const float bv = b1[nt * 16 + l16];
#pragma unroll
        for (int mt = 0; mt < 4; ++mt) {
            f32x4 c; c[0] = bv; c[1] = bv; c[2] = bv; c[3] = bv;
            acc[mt][nt] = c;
        }
    }

    // ---- layer-2 GEMM: 4 K-chunks of 32 ----
    for (int c = 0; c < 4; ++c) {
        if (c) __syncthreads();
#pragma unroll
        for (int kk = 0; kk < 32; ++kk) {
            const int k = c * 32 + kk;
            const float pre = fmaf(x0, W0[k], fmaf(x1, W0[128 + k], fmaf(x2, W0[256 + k], b0[k])));
            sbuf[kk * SA + tid] = packsplit(fast_tanh(pre));
        }
        __syncthreads();

        bf16x8 Bhi[4], Blo[4];
#pragma unroll
        for (int nt = 0; nt < 4; ++nt) {
            const uint4* p = (const uint4*)(W1pk + (nt * 16 + l16) * 128 + c * 32 + qd * 8);
            uint4 u0 = p[0], u1 = p[1];
            unsigned int w[8] = {u0.x, u0.y, u0.z, u0.w, u1.x, u1.y, u1.z, u1.w};
            unpack8(w, Bhi[nt], Blo[nt]);
        }
#pragma unroll
        for (int mt = 0; mt < 4; ++mt) {
            unsigned int a[8];
            const int mrow = wv * 64 + mt * 16 + l16;
#pragma unroll
            for (int j = 0; j < 8; ++j) a[j] = sbuf[(qd * 8 + j) * SA + mrow];
            bf16x8 Ahi, Alo;
            unpack8(a, Ahi, Alo);
#pragma unroll
            for (int nt = 0; nt < 4; ++nt) {
                acc[mt][nt] = __builtin_amdgcn_mfma_f32_16x16x32_bf16(Ahi, Bhi[nt], acc[mt][nt], 0, 0, 0);
                acc[mt][nt] = __builtin_amdgcn_mfma_f32_16x16x32_bf16(Ahi, Blo[nt], acc[mt][nt], 0, 0, 0);
                acc[mt][nt] = __builtin_amdgcn_mfma_f32_16x16x32_bf16(Alo, Bhi[nt], acc[mt][nt], 0, 0, 0);
            }
        }
    }

    // ---- expert-A accumulators, init ba (col = nt2*16 + l16) ----
    f32x4 acc2[4][2];
#pragma unroll
    for (int nt2 = 0; nt2 < 2; ++nt2) {
        const float bv = ba[(eid << 5) + nt2 * 16 + l16];
#pragma unroll
        for (int mt = 0; mt < 4; ++mt) {
            f32x4 c; c[0] = bv; c[1] = bv; c[2] = bv; c[3] = bv;
            acc2[mt][nt2] = c;
        }
    }

    // ---- expert-A GEMM: h2 = tanh(acc) restaged [d][sample]; 2 K-chunks ----
    for (int c2 = 0; c2 < 2; ++c2) {
        __syncthreads();
#pragma unroll
        for (int mt = 0; mt < 4; ++mt) {
#pragma unroll
            for (int ntl = 0; ntl < 2; ++ntl) {
#pragma unroll
                for (int r = 0; r < 4; ++r) {
                    const float h2 = fast_tanh(acc[mt][c2 * 2 + ntl][r]);
                    const int dl  = ntl * 16 + l16;             // local k
                    const int row = wv * 64 + mt * 16 + qd * 4 + r;
                    sbuf[dl * SA + row] = packsplit(h2);
                }
            }
        }
        __syncthreads();

        bf16x8 B2hi[2], B2lo[2];
#pragma unroll
        for (int nt2 = 0; nt2 < 2; ++nt2) {
            const uint4* p = (const uint4*)(Wapk + eid * 2048 + (nt2 * 16 + l16) * 64 + c2 * 32 + qd * 8);
            uint4 u0 = p[0], u1 = p[1];
            unsigned int w[8] = {u0.x, u0.y, u0.z, u0.w, u1.x, u1.y, u1.z, u1.w};
            unpack8(w, B2hi[nt2], B2lo[nt2]);
        }
#pragma unroll
        for (int mt = 0; mt < 4; ++mt) {
            unsigned int a[8];
            const int mrow = wv * 64 + mt * 16 + l16;
#pragma unroll
            for (int j = 0; j < 8; ++j) a[j] = sbuf[(qd * 8 + j) * SA + mrow];
            bf16x8 Ahi, Alo;
            unpack8(a, Ahi, Alo);
#pragma unroll
            for (int nt2 = 0; nt2 < 2; ++nt2) {
                acc2[mt][nt2] = __builtin_amdgcn_mfma_f32_16x16x32_bf16(Ahi, B2hi[nt2], acc2[mt][nt2], 0, 0, 0);
                acc2[mt][nt2] = __builtin_amdgcn_mfma_f32_16x16x32_bf16(Ahi, B2lo[nt2], acc2[mt][nt2], 0, 0, 0);
                acc2[mt][nt2] = __builtin_amdgcn_mfma_f32_16x16x32_bf16(Alo, B2hi[nt2], acc2[mt][nt2], 0, 0, 0);
            }
        }
    }

    // ---- g = tanh(acc2) staged [sample][h] (fp32), expert-B per-thread ----
    __syncthreads();
    float* g2 = (float*)sbuf;
#pragma unroll
    for (int mt = 0; mt < 4; ++mt) {
#pragma unroll
        for (int nt2 = 0; nt2 < 2; ++nt2) {
#pragma unroll
            for (int r = 0; r < 4; ++r) {
                const int row = wv * 64 + mt * 16 + qd * 4 + r;
                g2[row * SG + nt2 * 16 + l16] = fast_tanh(acc2[mt][nt2][r]);
            }
        }
    }
    __syncthreads();

    float gv[32];
    {
        const float4* grow = (const float4*)(g2 + tid * SG);
#pragma unroll
        for (int i = 0; i < 8; ++i) {
            float4 v = grow[i];
            gv[4 * i + 0] = v.x; gv[4 * i + 1] = v.y;
            gv[4 * i + 2] = v.z; gv[4 * i + 3] = v.w;
        }
    }

    const float* __restrict__ wbe = Wb + (eid << 6);
    float p0 = bb[2 * eid], p1 = bb[2 * eid + 1];
#pragma unroll
    for (int h = 0; h < 32; ++h) {
        p0 = fmaf(gv[h], wbe[2 * h + 0], p0);
        p1 = fmaf(gv[h], wbe[2 * h + 1], p1);
    }

    const float s = fmaf(p0, p0, fmaf(p1, p1, 1e-6f));
    const float inv = 1.0f / sqrtf(s);
    if (valid) {
        float2 o; o.x = p0 * inv; o.y = p1 * inv;
        ((float2*)out)[idx] = o;
    }
}

extern "C" void kernel_launch(void* const* d_in, const int* in_sizes, int n_in,
                              void* d_out, int out_size, void* d_ws, size_t ws_size,
                              hipStream_t stream) {
    const float* x  = (const float*)d_in[0];
    const int*   n  = (const int*)d_in[1];
    const int*   l  = (const int*)d_in[2];
    const int*   m  = (const int*)d_in[3];
    const float* W0 = (const float*)d_in[4];
    const float* b0 = (const float*)d_in[5];
    const float* W1 = (const float*)d_in[6];
    const float* b1 = (const float*)d_in[7];
    const float* Wa = (const float*)d_in[8];
    const float* ba = (const float*)d_in[9];
    const float* Wb = (const float*)d_in[10];
    const float* bb = (const float*)d_in[11];
    float* out = (float*)d_out;

    const int B = in_sizes[1];   // 262144

    // workspace layout (16B-aligned pieces)
    int*          perm = (int*)d_ws;                       // B
    int*          eids = perm + B;                         // B
    int4*         btab = (int4*)(eids + B);                // MAXBLK
    int*          hist = (int*)(btab + MAXBLK);            // HB*NE
    int*          base = hist + HB * NE;                   // HB*NE
    unsigned int* W1pk = (unsigned int*)(base + HB * NE);  // 64*128
    unsigned int* Wapk = W1pk + 64 * 128;                  // 30*2048

    hist_pack_kernel<<<HB + 4 + NE, 256, 0, stream>>>(n, l, m, hist, eids, W1, W1pk, Wa, Wapk, B);
    plan_kernel<<<1, 256, 0, stream>>>(hist, base, btab);
    scatter_kernel<<<HB, 256, 0, stream>>>(eids, base, perm, B);
    wfc_kernel<<<MAXBLK, THREADS, 0, stream>>>(
        x, perm, btab, W0, b0, W1pk, b1, Wapk, ba, Wb, bb, out);
}

// Round 7
// 146.371 us; speedup vs baseline: 7.4531x; 1.0505x over previous
//
#include <hip/hip_runtime.h>
#include <math.h>

// WfcNN: B=262144.
//   h1 = tanh(x @ W0 + b0)            (B,128)
//   h2 = tanh(h1 @ W1 + b1)           (B,64)
//   g  = tanh(h2 . Wa[eid] + ba[eid]) (B,32)
//   psi= g . Wb[eid] + bb[eid]        (B,2) ; out = psi / sqrt(|psi|^2+1e-6)
//
// Round 7: prep restructure + B-operand pre-splitting.
//  - plan_kernel/btab eliminated: K1 hist ends with
//    bbase[bx][e]=atomicAdd(&etot[e],h[e]); K2 scans 30 totals locally;
//    wfc derives (eid,start,cnt) from etot with a uniform 30-iter scalar scan.
//    One fewer launch, no single-block serial kernel.
//  - W1/Wa pre-split into SEPARATE hi/lo planes already in MFMA B-fragment
//    order -> wfc loads bf16x8 directly (no unpack ALU for B).
//  - Both GEMMs stay on MFMA 3-pass split-bf16 (validated R5/R6, absmax
//    0.0039 unchanged). A-side staging layout unchanged (conflict-free).

#define THREADS 256
#define NE 30
#define HB 128
#define MAXBLK 1056
#define SA 259            // u32 row stride for [k][sample] staging
#define SG 36             // f32 row stride for [sample][h] g staging

typedef short bf16x8 __attribute__((ext_vector_type(8)));
typedef float f32x4 __attribute__((ext_vector_type(4)));

__device__ __forceinline__ int expert_id(int nn, int ll, int mm) {
    return ((nn - 1) * nn * (2 * nn - 1)) / 6 + ll * ll + ll + mm;
}

// tanh(v) = 1 - 2/(exp2(2*log2e*v)+1); saturates correctly, no clamp. 5 ops.
__device__ __forceinline__ float fast_tanh(float v) {
    float e = __builtin_exp2f(v * 2.885390082f);
    return fmaf(-2.0f, __builtin_amdgcn_rcpf(e + 1.0f), 1.0f);
}

__device__ __forceinline__ unsigned int f2b(float f) {   // f32 -> bf16 RNE
    unsigned int u = __float_as_uint(f);
    return (u + 0x7fffu + ((u >> 16) & 1u)) >> 16;
}
__device__ __forceinline__ float b2f(unsigned int b) {
    return __uint_as_float(b << 16);
}
__device__ __forceinline__ unsigned int packsplit(float v) {
    unsigned int hb = f2b(v);
    unsigned int lb = f2b(v - b2f(hb));
    return (lb << 16) | hb;
}

union U8 { unsigned int u[4]; bf16x8 v; };
__device__ __forceinline__ void unpack8(const unsigned int* w, bf16x8& hi, bf16x8& lo) {
    U8 H, L;
#pragma unroll
    for (int i = 0; i < 4; ++i) {
        H.u[i] = (w[2 * i + 1] << 16) | (w[2 * i] & 0xffffu);
        L.u[i] = (w[2 * i + 1] & 0xffff0000u) | (w[2 * i] >> 16);
    }
    hi = H.v; lo = L.v;
}

// ---- K1: hist + eid cache + bucket base reservation + weight splitting ----
__global__ void hist_pack_kernel(const int* __restrict__ nq, const int* __restrict__ lq,
                                 const int* __restrict__ mq,
                                 int* __restrict__ eids, int* __restrict__ etot,
                                 int* __restrict__ bbase,
                                 const float* __restrict__ W1,
                                 unsigned short* __restrict__ W1fh, unsigned short* __restrict__ W1fl,
                                 const float* __restrict__ Wa,
                                 unsigned short* __restrict__ Wafh, unsigned short* __restrict__ Wafl,
                                 int B) {
    const int tid = threadIdx.x;
    const int bx = blockIdx.x;
    if (bx < HB) {
        __shared__ int h[NE];
        if (tid < NE) h[tid] = 0;
        __syncthreads();
        const int per = B / HB, base = bx * per;
        for (int i = tid; i < per; i += blockDim.x) {
            const int e = expert_id(nq[base + i], lq[base + i], mq[base + i]);
            eids[base + i] = e;
            atomicAdd(&h[e], 1);
        }
        __syncthreads();
        if (tid < NE) bbase[bx * NE + tid] = atomicAdd(&etot[tid], h[tid]);
    } else if (bx == HB) {
        // W1 (128,64) -> hi/lo planes in B-fragment order:
        // rec = ((c*4+nt)*4+qd)*16 + l16 ; elem j ; k=c*32+qd*8+j ; n=nt*16+l16
        for (int i = tid; i < 8192; i += blockDim.x) {
            const int j = i & 7, l16 = (i >> 3) & 15, qd = (i >> 7) & 3;
            const int nt = (i >> 9) & 3, c = i >> 11;
            const int k = c * 32 + qd * 8 + j, n = nt * 16 + l16;
            const float w = W1[k * 64 + n];
            const unsigned int hb = f2b(w);
            W1fh[i] = (unsigned short)hb;
            W1fl[i] = (unsigned short)f2b(w - b2f(hb));
        }
    } else {
        // Wa[e] (64,32) -> hi/lo planes, rec = ((c2*2+nt2)*4+qd)*16 + l16
        const int e = bx - HB - 1;
        for (int i = tid; i < 2048; i += blockDim.x) {
            const int j = i & 7, l16 = (i >> 3) & 15, qd = (i >> 7) & 3;
            const int nt2 = (i >> 9) & 1, c2 = (i >> 10) & 1;
            const int d = c2 * 32 + qd * 8 + j, hh = nt2 * 16 + l16;
            const float w = Wa[e * 2048 + d * 32 + hh];
            const unsigned int hb = f2b(w);
            Wafh[e * 2048 + i] = (unsigned short)hb;
            Wafl[e * 2048 + i] = (unsigned short)f2b(w - b2f(hb));
        }
    }
}

// ---- K2: scatter into sorted order (local scan of 30 totals, no plan) ----
__global__ void scatter_kernel(const int* __restrict__ eids, const int* __restrict__ etot,
                               const int* __restrict__ bbase, int* __restrict__ perm, int B) {
    __shared__ int lcnt[NE], esrt[NE], bb[NE];
    const int tid = threadIdx.x;
    if (tid < NE) { lcnt[tid] = 0; bb[tid] = bbase[blockIdx.x * NE + tid]; }
    if (tid == 0) {
        int es = 0;
        for (int e = 0; e < NE; ++e) { esrt[e] = es; es += etot[e]; }
    }
    __syncthreads();
    const int per = B / gridDim.x;
    const int blk = blockIdx.x * per;
    for (int i = tid; i < per; i += blockDim.x) {
        const int idx = blk + i;
        const int e = eids[idx];
        const int r = atomicAdd(&lcnt[e], 1);
        perm[esrt[e] + bb[e] + r] = idx;
    }
}

// ---- K3: fused MLP; layer2 + expert-A on MFMA (3-pass split-bf16) ----
__global__ __launch_bounds__(THREADS, 3) void wfc_kernel(
    const float* __restrict__ x, const int* __restrict__ perm,
    const int* __restrict__ etot,
    const float* __restrict__ W0, const float* __restrict__ b0,
    const bf16x8* __restrict__ W1fh, const bf16x8* __restrict__ W1fl,
    const float* __restrict__ b1,
    const bf16x8* __restrict__ Wafh, const bf16x8* __restrict__ Wafl,
    const float* __restrict__ ba,
    const float* __restrict__ Wb, const float* __restrict__ bb,
    float* __restrict__ out)
{
    __shared__ unsigned int sbuf[9216];      // 36,864 B staging

    // derive (eid, start, cnt) from etot: uniform scalar 30-iter scan
    int eid = -1, start = 0, cnt = 0;
    {
        int cum = 0, es = 0;
#pragma unroll 1
        for (int e = 0; e < NE; ++e) {
            const int t = etot[e];
            const int nb = (t + THREADS - 1) >> 8;
            if ((int)blockIdx.x < cum + nb) {
                const int seg = blockIdx.x - cum;
                eid = e; start = es + seg * THREADS; cnt = min(THREADS, t - seg * THREADS);
                break;
            }
            cum += nb; es += t;
        }
    }
    if (eid < 0) return;
    eid = __builtin_amdgcn_readfirstlane(eid);

    const int tid = threadIdx.x;
    const bool valid = tid < cnt;
    const int idx = perm[start + (valid ? tid : 0)];

    const int lane = tid & 63;
    const int wv   = tid >> 6;
    const int qd   = lane >> 4;
    const int l16  = lane & 15;

    const float x0 = x[idx * 3 + 0];
    const float x1 = x[idx * 3 + 1];
    const float x2 = x[idx * 3 + 2];

    // ---- layer 2 accumulators, init b1 (C layout: col = l16) ----
    f32x4 acc[4][4];
#pragma unroll
    for (int nt = 0; nt < 4; ++nt) {
        const float bv = b1[nt * 16 + l16];
#pragma unroll
        for (int mt = 0; mt < 4; ++mt) {
            f32x4 c; c[0] = bv; c[1] = bv; c[2] = bv; c[3] = bv;
            acc[mt][nt] = c;
        }
    }

    // ---- layer-2 GEMM: 4 K-chunks of 32 ----
    for (int c = 0; c < 4; ++c) {
        if (c) __syncthreads();
#pragma unroll
        for (int kk = 0; kk < 32; ++kk) {
            const int k = c * 32 + kk;
            const float pre = fmaf(x0, W0[k], fmaf(x1, W0[128 + k], fmaf(x2, W0[256 + k], b0[k])));
            sbuf[kk * SA + tid] = packsplit(fast_tanh(pre));
        }
        __syncthreads();

        bf16x8 Bhi[4], Blo[4];
#pragma unroll
        for (int nt = 0; nt < 4; ++nt) {
            const int rec = (c * 4 + nt) * 64 + qd * 16 + l16;
            Bhi[nt] = W1fh[rec];
            Blo[nt] = W1fl[rec];
        }
#pragma unroll
        for (int mt = 0; mt < 4; ++mt) {
            unsigned int a[8];
            const int mrow = wv * 64 + mt * 16 + l16;
#pragma unroll
            for (int j = 0; j < 8; ++j) a[j] = sbuf[(qd * 8 + j) * SA + mrow];
            bf16x8 Ahi, Alo;
            unpack8(a, Ahi, Alo);
#pragma unroll
            for (int nt = 0; nt < 4; ++nt) {
                acc[mt][nt] = __builtin_amdgcn_mfma_f32_16x16x32_bf16(Ahi, Bhi[nt], acc[mt][nt], 0, 0, 0);
                acc[mt][nt] = __builtin_amdgcn_mfma_f32_16x16x32_bf16(Ahi, Blo[nt], acc[mt][nt], 0, 0, 0);
                acc[mt][nt] = __builtin_amdgcn_mfma_f32_16x16x32_bf16(Alo, Bhi[nt], acc[mt][nt], 0, 0, 0);
            }
        }
    }

    // ---- expert-A accumulators, init ba ----
    f32x4 acc2[4][2];
#pragma unroll
    for (int nt2 = 0; nt2 < 2; ++nt2) {
        const float bv = ba[(eid << 5) + nt2 * 16 + l16];
#pragma unroll
        for (int mt = 0; mt < 4; ++mt) {
            f32x4 c; c[0] = bv; c[1] = bv; c[2] = bv; c[3] = bv;
            acc2[mt][nt2] = c;
        }
    }

    // ---- expert-A GEMM: h2 = tanh(acc) restaged [d][sample]; 2 K-chunks ----
    const bf16x8* __restrict__ waeh = Wafh + (eid << 8);
    const bf16x8* __restrict__ wael = Wafl + (eid << 8);
    for (int c2 = 0; c2 < 2; ++c2) {
        __syncthreads();
#pragma unroll
        for (int mt = 0; mt < 4; ++mt) {
#pragma unroll
            for (int ntl = 0; ntl < 2; ++ntl) {
#pragma unroll
                for (int r = 0; r < 4; ++r) {
                    const float h2 = fast_tanh(acc[mt][c2 * 2 + ntl][r]);
                    const int dl  = ntl * 16 + l16;
                    const int row = wv * 64 + mt * 16 + qd * 4 + r;
                    sbuf[dl * SA + row] = packsplit(h2);
                }
            }
        }
        __syncthreads();

        bf16x8 B2hi[2], B2lo[2];
#pragma unroll
        for (int nt2 = 0; nt2 < 2; ++nt2) {
            const int rec = (c2 * 2 + nt2) * 64 + qd * 16 + l16;
            B2hi[nt2] = waeh[rec];
            B2lo[nt2] = wael[rec];
        }
#pragma unroll
        for (int mt = 0; mt < 4; ++mt) {
            unsigned int a[8];
            const int mrow = wv * 64 + mt * 16 + l16;
#pragma unroll
            for (int j = 0; j < 8; ++j) a[j] = sbuf[(qd * 8 + j) * SA + mrow];
            bf16x8 Ahi, Alo;
            unpack8(a, Ahi, Alo);
#pragma unroll
            for (int nt2 = 0; nt2 < 2; ++nt2) {
                acc2[mt][nt2] = __builtin_amdgcn_mfma_f32_16x16x32_bf16(Ahi, B2hi[nt2], acc2[mt][nt2], 0, 0, 0);
                acc2[mt][nt2] = __builtin_amdgcn_mfma_f32_16x16x32_bf16(Ahi, B2lo[nt2], acc2[mt][nt2], 0, 0, 0);
                acc2[mt][nt2] = __builtin_amdgcn_mfma_f32_16x16x32_bf16(Alo, B2hi[nt2], acc2[mt][nt2], 0, 0, 0);
            }
        }
    }

    // ---- g = tanh(acc2) staged [sample][h], expert-B per-thread ----
    __syncthreads();
    float* g2 = (float*)sbuf;
#pragma unroll
    for (int mt = 0; mt < 4; ++mt) {
#pragma unroll
        for (int nt2 = 0; nt2 < 2; ++nt2) {
#pragma unroll
            for (int r = 0; r < 4; ++r) {
                const int row = wv * 64 + mt * 16 + qd * 4 + r;
                g2[row * SG + nt2 * 16 + l16] = fast_tanh(acc2[mt][nt2][r]);
            }
        }
    }
    __syncthreads();

    float gv[32];
    {
        const float4* grow = (const float4*)(g2 + tid * SG);
#pragma unroll
        for (int i = 0; i < 8; ++i) {
            float4 v = grow[i];
            gv[4 * i + 0] = v.x; gv[4 * i + 1] = v.y;
            gv[4 * i + 2] = v.z; gv[4 * i + 3] = v.w;
        }
    }

    const float* __restrict__ wbe = Wb + (eid << 6);
    float p0 = bb[2 * eid], p1 = bb[2 * eid + 1];
#pragma unroll
    for (int h = 0; h < 32; ++h) {
        p0 = fmaf(gv[h], wbe[2 * h + 0], p0);
        p1 = fmaf(gv[h], wbe[2 * h + 1], p1);
    }

    const float s = fmaf(p0, p0, fmaf(p1, p1, 1e-6f));
    const float inv = 1.0f / sqrtf(s);
    if (valid) {
        float2 o; o.x = p0 * inv; o.y = p1 * inv;
        ((float2*)out)[idx] = o;
    }
}

extern "C" void kernel_launch(void* const* d_in, const int* in_sizes, int n_in,
                              void* d_out, int out_size, void* d_ws, size_t ws_size,
                              hipStream_t stream) {
    const float* x  = (const float*)d_in[0];
    const int*   n  = (const int*)d_in[1];
    const int*   l  = (const int*)d_in[2];
    const int*   m  = (const int*)d_in[3];
    const float* W0 = (const float*)d_in[4];
    const float* b0 = (const float*)d_in[5];
    const float* W1 = (const float*)d_in[6];
    const float* b1 = (const float*)d_in[7];
    const float* Wa = (const float*)d_in[8];
    const float* ba = (const float*)d_in[9];
    const float* Wb = (const float*)d_in[10];
    const float* bb = (const float*)d_in[11];
    float* out = (float*)d_out;

    const int B = in_sizes[1];   // 262144

    // workspace layout (all segments 16B aligned)
    int*            perm = (int*)d_ws;                       // B
    int*            eids = perm + B;                         // B
    int*            bbase = eids + B;                        // HB*NE = 3840
    int*            etot  = bbase + HB * NE;                 // 32 (16B-mult)
    unsigned short* W1fh  = (unsigned short*)(etot + 32);    // 8192 u16
    unsigned short* W1fl  = W1fh + 8192;                     // 8192 u16
    unsigned short* Wafh  = W1fl + 8192;                     // 30*2048 u16
    unsigned short* Wafl  = Wafh + NE * 2048;                // 30*2048 u16

    hipMemsetAsync(etot, 0, 32 * sizeof(int), stream);
    hist_pack_kernel<<<HB + 1 + NE, 256, 0, stream>>>(
        n, l, m, eids, etot, bbase, W1, W1fh, W1fl, Wa, Wafh, Wafl, B);
    scatter_kernel<<<HB, 256, 0, stream>>>(eids, etot, bbase, perm, B);
    wfc_kernel<<<MAXBLK, THREADS, 0, stream>>>(
        x, perm, etot, W0, b0,
        (const bf16x8*)W1fh, (const bf16x8*)W1fl, b1,
        (const bf16x8*)Wafh, (const bf16x8*)Wafl, ba, Wb, bb, out);
}

// Round 9
// 140.865 us; speedup vs baseline: 7.7445x; 1.0391x over previous
//
#include <hip/hip_runtime.h>
#include <math.h>

// WfcNN: B=262144.
//   h1 = tanh(x @ W0 + b0)            (B,128)
//   h2 = tanh(h1 @ W1 + b1)           (B,64)
//   g  = tanh(h2 . Wa[eid] + ba[eid]) (B,32)
//   psi= g . Wb[eid] + bb[eid]        (B,2) ; out = psi / sqrt(|psi|^2+1e-6)
//
// Round 9: R7 structure (3 kernels + memset; cooperative fusion FAILED in
// R8 -- hipLaunchCooperativeKernel errors in this harness, do not retry)
// + two VALU trims in the compute kernel:
//   - unpack8 via v_perm_b32 (bit-identical byte select, 8 ops vs ~14)
//   - runtime packsplit: RNE hi + TRUNCATED lo (~8 ops vs 14; element error
//     2^-17 vs 2^-18 -- absmax has sat at the harness 2^-8 floor since R1)
// Weight planes keep full RNE splitting (prep-time, free).
// Both GEMMs on MFMA 3-pass split-bf16 (validated R5-R7).

#define THREADS 256
#define NE 30
#define HB 128
#define MAXBLK 1056
#define SA 259            // u32 row stride for [k][sample] staging
#define SG 36             // f32 row stride for [sample][h] g staging

typedef short bf16x8 __attribute__((ext_vector_type(8)));
typedef float f32x4 __attribute__((ext_vector_type(4)));

__device__ __forceinline__ int expert_id(int nn, int ll, int mm) {
    return ((nn - 1) * nn * (2 * nn - 1)) / 6 + ll * ll + ll + mm;
}

// tanh(v) = 1 - 2/(exp2(2*log2e*v)+1); saturates correctly, no clamp.
__device__ __forceinline__ float fast_tanh(float v) {
    float e = __builtin_exp2f(v * 2.885390082f);
    return fmaf(-2.0f, __builtin_amdgcn_rcpf(e + 1.0f), 1.0f);
}

__device__ __forceinline__ unsigned int f2b(float f) {   // f32 -> bf16 RNE
    unsigned int u = __float_as_uint(f);
    return (u + 0x7fffu + ((u >> 16) & 1u)) >> 16;
}
__device__ __forceinline__ float b2f(unsigned int b) {
    return __uint_as_float(b << 16);
}
// runtime split: RNE hi, truncated lo; packed (lo16<<16)|hi16
__device__ __forceinline__ unsigned int packsplit(float v) {
    const unsigned int hb = f2b(v);
    const float lo = v - b2f(hb);
    return (__float_as_uint(lo) & 0xffff0000u) | hb;
}

union U8 { unsigned int u[4]; bf16x8 v; };
// packed words -> hi-plane / lo-plane bf16x8 (bit-identical to shift/mask form)
__device__ __forceinline__ void unpack8(const unsigned int* w, bf16x8& hi, bf16x8& lo) {
    U8 H, L;
#pragma unroll
    for (int i = 0; i < 4; ++i) {
        H.u[i] = __builtin_amdgcn_perm(w[2 * i + 1], w[2 * i], 0x05040100u);
        L.u[i] = __builtin_amdgcn_perm(w[2 * i + 1], w[2 * i], 0x07060302u);
    }
    hi = H.v; lo = L.v;
}

// ---- K1: hist + eid cache + bucket base reservation + weight splitting ----
__global__ void hist_pack_kernel(const int* __restrict__ nq, const int* __restrict__ lq,
                                 const int* __restrict__ mq,
                                 int* __restrict__ eids, int* __restrict__ etot,
                                 int* __restrict__ bbase,
                                 const float* __restrict__ W1,
                                 unsigned short* __restrict__ W1fh, unsigned short* __restrict__ W1fl,
                                 const float* __restrict__ Wa,
                                 unsigned short* __restrict__ Wafh, unsigned short* __restrict__ Wafl,
                                 int B) {
    const int tid = threadIdx.x;
    const int bx = blockIdx.x;
    if (bx < HB) {
        __shared__ int h[NE];
        if (tid < NE) h[tid] = 0;
        __syncthreads();
        const int per = B / HB, base = bx * per;
        for (int i = tid; i < per; i += blockDim.x) {
            const int e = expert_id(nq[base + i], lq[base + i], mq[base + i]);
            eids[base + i] = e;
            atomicAdd(&h[e], 1);
        }
        __syncthreads();
        if (tid < NE) bbase[bx * NE + tid] = atomicAdd(&etot[tid], h[tid]);
    } else if (bx == HB) {
        // W1 (128,64) -> hi/lo planes in B-frag order (rec=((c*4+nt)*4+qd)*16+l16)
        for (int i = tid; i < 8192; i += blockDim.x) {
            const int j = i & 7, s = (i >> 3) & 15, q = (i >> 7) & 3;
            const int nt = (i >> 9) & 3, c = i >> 11;
            const int k = c * 32 + q * 8 + j, n = nt * 16 + s;
            const float w = W1[k * 64 + n];
            const unsigned int hb = f2b(w);
            W1fh[i] = (unsigned short)hb;
            W1fl[i] = (unsigned short)f2b(w - b2f(hb));
        }
    } else {
        // Wa[e] (64,32) -> hi/lo planes (rec=((c2*2+nt2)*4+qd)*16+l16)
        const int e = bx - HB - 1;
        for (int i = tid; i < 2048; i += blockDim.x) {
            const int j = i & 7, s = (i >> 3) & 15, q = (i >> 7) & 3;
            const int nt2 = (i >> 9) & 1, c2 = (i >> 10) & 1;
            const int d = c2 * 32 + q * 8 + j, hh = nt2 * 16 + s;
            const float w = Wa[e * 2048 + d * 32 + hh];
            const unsigned int hb = f2b(w);
            Wafh[e * 2048 + i] = (unsigned short)hb;
            Wafl[e * 2048 + i] = (unsigned short)f2b(w - b2f(hb));
        }
    }
}

// ---- K2: scatter into sorted order (local scan of 30 totals) ----
__global__ void scatter_kernel(const int* __restrict__ eids, const int* __restrict__ etot,
                               const int* __restrict__ bbase, int* __restrict__ perm, int B) {
    __shared__ int lcnt[NE], esrt[NE], bb[NE];
    const int tid = threadIdx.x;
    if (tid < NE) { lcnt[tid] = 0; bb[tid] = bbase[blockIdx.x * NE + tid]; }
    if (tid == 0) {
        int es = 0;
        for (int e = 0; e < NE; ++e) { esrt[e] = es; es += etot[e]; }
    }
    __syncthreads();
    const int per = B / gridDim.x;
    const int blk = blockIdx.x * per;
    for (int i = tid; i < per; i += blockDim.x) {
        const int idx = blk + i;
        const int e = eids[idx];
        const int r = atomicAdd(&lcnt[e], 1);
        perm[esrt[e] + bb[e] + r] = idx;
    }
}

// ---- K3: fused MLP; layer2 + expert-A on MFMA (3-pass split-bf16) ----
__global__ __launch_bounds__(THREADS, 3) void wfc_kernel(
    const float* __restrict__ x, const int* __restrict__ perm,
    const int* __restrict__ etot,
    const float* __restrict__ W0, const float* __restrict__ b0,
    const bf16x8* __restrict__ W1fh, const bf16x8* __restrict__ W1fl,
    const float* __restrict__ b1,
    const bf16x8* __restrict__ Wafh, const bf16x8* __restrict__ Wafl,
    const float* __restrict__ ba,
    const float* __restrict__ Wb, const float* __restrict__ bb,
    float* __restrict__ out)
{
    __shared__ unsigned int sbuf[9216];      // 36,864 B staging

    // derive (eid, start, cnt) from etot: uniform scalar 30-iter scan
    int eid = -1, start = 0, cnt = 0;
    {
        int cum = 0, es = 0;
#pragma unroll 1
        for (int e = 0; e < NE; ++e) {
            const int t = etot[e];
            const int nb = (t + THREADS - 1) >> 8;
            if ((int)blockIdx.x < cum + nb) {
                const int seg = blockIdx.x - cum;
                eid = e; start = es + seg * THREADS; cnt = min(THREADS, t - seg * THREADS);
                break;
            }
            cum += nb; es += t;
        }
    }
    if (eid < 0) return;
    eid = __builtin_amdgcn_readfirstlane(eid);

    const int tid = threadIdx.x;
    const bool valid = tid < cnt;
    const int idx = perm[start + (valid ? tid : 0)];

    const int lane = tid & 63;
    const int wv   = tid >> 6;
    const int qd   = lane >> 4;
    const int l16  = lane & 15;

    const float x0 = x[idx * 3 + 0];
    const float x1 = x[idx * 3 + 1];
    const float x2 = x[idx * 3 + 2];

    // ---- layer 2 accumulators, init b1 (C layout: col = l16) ----
    f32x4 acc[4][4];
#pragma unroll
    for (int nt = 0; nt < 4; ++nt) {
        const float bv = b1[nt * 16 + l16];
#pragma unroll
        for (int mt = 0; mt < 4; ++mt) {
            f32x4 c; c[0] = bv; c[1] = bv; c[2] = bv; c[3] = bv;
            acc[mt][nt] = c;
        }
    }

    // ---- layer-2 GEMM: 4 K-chunks of 32 ----
    for (int c = 0; c < 4; ++c) {
        if (c) __syncthreads();
#pragma unroll
        for (int kk = 0; kk < 32; ++kk) {
            const int k = c * 32 + kk;
            const float pre = fmaf(x0, W0[k], fmaf(x1, W0[128 + k], fmaf(x2, W0[256 + k], b0[k])));
            sbuf[kk * SA + tid] = packsplit(fast_tanh(pre));
        }
        __syncthreads();

        bf16x8 Bhi[4], Blo[4];
#pragma unroll
        for (int nt = 0; nt < 4; ++nt) {
            const int rec = (c * 4 + nt) * 64 + qd * 16 + l16;
            Bhi[nt] = W1fh[rec];
            Blo[nt] = W1fl[rec];
        }
#pragma unroll
        for (int mt = 0; mt < 4; ++mt) {
            unsigned int a[8];
            const int mrow = wv * 64 + mt * 16 + l16;
#pragma unroll
            for (int j = 0; j < 8; ++j) a[j] = sbuf[(qd * 8 + j) * SA + mrow];
            bf16x8 Ahi, Alo;
            unpack8(a, Ahi, Alo);
#pragma unroll
            for (int nt = 0; nt < 4; ++nt) {
                acc[mt][nt] = __builtin_amdgcn_mfma_f32_16x16x32_bf16(Ahi, Bhi[nt], acc[mt][nt], 0, 0, 0);
                acc[mt][nt] = __builtin_amdgcn_mfma_f32_16x16x32_bf16(Ahi, Blo[nt], acc[mt][nt], 0, 0, 0);
                acc[mt][nt] = __builtin_amdgcn_mfma_f32_16x16x32_bf16(Alo, Bhi[nt], acc[mt][nt], 0, 0, 0);
            }
        }
    }

    // ---- expert-A accumulators, init ba ----
    f32x4 acc2[4][2];
#pragma unroll
    for (int nt2 = 0; nt2 < 2; ++nt2) {
        const float bv = ba[(eid << 5) + nt2 * 16 + l16];
#pragma unroll
        for (int mt = 0; mt < 4; ++mt) {
            f32x4 c; c[0] = bv; c[1] = bv; c[2] = bv; c[3] = bv;
            acc2[mt][nt2] = c;
        }
    }

    // ---- expert-A GEMM: h2 = tanh(acc) restaged [d][sample]; 2 K-chunks ----
    const bf16x8* __restrict__ waeh = Wafh + (eid << 8);
    const bf16x8* __restrict__ wael = Wafl + (eid << 8);
    for (int c2 = 0; c2 < 2; ++c2) {
        __syncthreads();
#pragma unroll
        for (int mt = 0; mt < 4; ++mt) {
#pragma unroll
            for (int ntl = 0; ntl < 2; ++ntl) {
#pragma unroll
                for (int r = 0; r < 4; ++r) {
                    const float h2 = fast_tanh(acc[mt][c2 * 2 + ntl][r]);
                    const int dl  = ntl * 16 + l16;
                    const int row = wv * 64 + mt * 16 + qd * 4 + r;
                    sbuf[dl * SA + row] = packsplit(h2);
                }
            }
        }
        __syncthreads();

        bf16x8 B2hi[2], B2lo[2];
#pragma unroll
        for (int nt2 = 0; nt2 < 2; ++nt2) {
            const int rec = (c2 * 2 + nt2) * 64 + qd * 16 + l16;
            B2hi[nt2] = waeh[rec];
            B2lo[nt2] = wael[rec];
        }
#pragma unroll
        for (int mt = 0; mt < 4; ++mt) {
            unsigned int a[8];
            const int mrow = wv * 64 + mt * 16 + l16;
#pragma unroll
            for (int j = 0; j < 8; ++j) a[j] = sbuf[(qd * 8 + j) * SA + mrow];
            bf16x8 Ahi, Alo;
            unpack8(a, Ahi, Alo);
#pragma unroll
            for (int nt2 = 0; nt2 < 2; ++nt2) {
                acc2[mt][nt2] = __builtin_amdgcn_mfma_f32_16x16x32_bf16(Ahi, B2hi[nt2], acc2[mt][nt2], 0, 0, 0);
                acc2[mt][nt2] = __builtin_amdgcn_mfma_f32_16x16x32_bf16(Ahi, B2lo[nt2], acc2[mt][nt2], 0, 0, 0);
                acc2[mt][nt2] = __builtin_amdgcn_mfma_f32_16x16x32_bf16(Alo, B2hi[nt2], acc2[mt][nt2], 0, 0, 0);
            }
        }
    }

    // ---- g = tanh(acc2) staged [sample][h], expert-B per-thread ----
    __syncthreads();
    float* g2 = (float*)sbuf;
#pragma unroll
    for (int mt = 0; mt < 4; ++mt) {
#pragma unroll
        for (int nt2 = 0; nt2 < 2; ++nt2) {
#pragma unroll
            for (int r = 0; r < 4; ++r) {
                const int row = wv * 64 + mt * 16 + qd * 4 + r;
                g2[row * SG + nt2 * 16 + l16] = fast_tanh(acc2[mt][nt2][r]);
            }
        }
    }
    __syncthreads();

    float gv[32];
    {
        const float4* grow = (const float4*)(g2 + tid * SG);
#pragma unroll
        for (int i = 0; i < 8; ++i) {
            float4 v = grow[i];
            gv[4 * i + 0] = v.x; gv[4 * i + 1] = v.y;
            gv[4 * i + 2] = v.z; gv[4 * i + 3] = v.w;
        }
    }

    const float* __restrict__ wbe = Wb + (eid << 6);
    float p0 = bb[2 * eid], p1 = bb[2 * eid + 1];
#pragma unroll
    for (int h = 0; h < 32; ++h) {
        p0 = fmaf(gv[h], wbe[2 * h + 0], p0);
        p1 = fmaf(gv[h], wbe[2 * h + 1], p1);
    }

    const float s = fmaf(p0, p0, fmaf(p1, p1, 1e-6f));
    const float inv = 1.0f / sqrtf(s);
    if (valid) {
        float2 o; o.x = p0 * inv; o.y = p1 * inv;
        ((float2*)out)[idx] = o;
    }
}

extern "C" void kernel_launch(void* const* d_in, const int* in_sizes, int n_in,
                              void* d_out, int out_size, void* d_ws, size_t ws_size,
                              hipStream_t stream) {
    const float* x  = (const float*)d_in[0];
    const int*   n  = (const int*)d_in[1];
    const int*   l  = (const int*)d_in[2];
    const int*   m  = (const int*)d_in[3];
    const float* W0 = (const float*)d_in[4];
    const float* b0 = (const float*)d_in[5];
    const float* W1 = (const float*)d_in[6];
    const float* b1 = (const float*)d_in[7];
    const float* Wa = (const float*)d_in[8];
    const float* ba = (const float*)d_in[9];
    const float* Wb = (const float*)d_in[10];
    const float* bb = (const float*)d_in[11];
    float* out = (float*)d_out;

    const int B = in_sizes[1];   // 262144

    // workspace layout (all segments 16B aligned)
    int*            perm  = (int*)d_ws;                      // B
    int*            eids  = perm + B;                        // B
    int*            bbase = eids + B;                        // HB*NE = 3840
    int*            etot  = bbase + HB * NE;                 // 32
    unsigned short* W1fh  = (unsigned short*)(etot + 32);    // 8192 u16
    unsigned short* W1fl  = W1fh + 8192;                     // 8192 u16
    unsigned short* Wafh  = W1fl + 8192;                     // 30*2048 u16
    unsigned short* Wafl  = Wafh + NE * 2048;                // 30*2048 u16

    hipMemsetAsync(etot, 0, 32 * sizeof(int), stream);
    hist_pack_kernel<<<HB + 1 + NE, 256, 0, stream>>>(
        n, l, m, eids, etot, bbase, W1, W1fh, W1fl, Wa, Wafh, Wafl, B);
    scatter_kernel<<<HB, 256, 0, stream>>>(eids, etot, bbase, perm, B);
    wfc_kernel<<<MAXBLK, THREADS, 0, stream>>>(
        x, perm, etot, W0, b0,
        (const bf16x8*)W1fh, (const bf16x8*)W1fl, b1,
        (const bf16x8*)Wafh, (const bf16x8*)Wafl, ba, Wb, bb, out);
}